// Round 1
// baseline (680.879 us; speedup 1.0000x reference)
//
#include <hip/hip_runtime.h>
#include <cstdint>
#include <cstddef>

#define NEXP 4
#define CH   128      // c_
#define C1   256
#define C2   256
#define HWSZ 6400     // 80*80
#define NTOKS 204800  // 32*6400
#define BNE  1e-3f

using f32x4 = __attribute__((ext_vector_type(4))) float;
using f16x8 = __attribute__((ext_vector_type(8))) _Float16;
using s16x8 = __attribute__((ext_vector_type(8))) short;

static __device__ __forceinline__ unsigned short f2bf(float f) {
    union { float f; unsigned u; } v; v.f = f;
    unsigned r = v.u + 0x7fffu + ((v.u >> 16) & 1u);
    return (unsigned short)(r >> 16);
}
static __device__ __forceinline__ f32x4 zero4() {
    f32x4 z; z[0] = 0.f; z[1] = 0.f; z[2] = 0.f; z[3] = 0.f; return z;
}

// ---------------------------------------------------------------- k0: pack center taps ew[:,:,:,1,1] -> bf16 [e][o][c]
__global__ __launch_bounds__(256) void k0_pack_center(const float* __restrict__ ew,
                                                      unsigned short* __restrict__ cen) {
    int idx = blockIdx.x * 256 + threadIdx.x;          // (e*128+o)*128+c
    if (idx < NEXP * CH * CH) cen[idx] = f2bf(ew[(size_t)idx * 9 + 4]);
}

// ---------------------------------------------------------------- k1: conv1 (fp16x2-split MFMA) + BN + SiLU + router
// grid: 3200 blocks, 64 tokens each. A = w1 (128x256), B = x slice (256x64), D = y1 (128 x 64tok).
__global__ __launch_bounds__(256, 2) void k1_conv1_router(
    const float* __restrict__ x, const float* __restrict__ w1,
    const float* __restrict__ bn1_g, const float* __restrict__ bn1_b,
    const float* __restrict__ bn1_m, const float* __restrict__ bn1_v,
    const float* __restrict__ rw, const float* __restrict__ rb,
    unsigned short* __restrict__ tokens, float* __restrict__ wd)
{
    const int tid  = threadIdx.x;
    const int lane = tid & 63;
    const int wv   = tid >> 6;      // wave 0..3
    const int n15  = lane & 15;
    const int quad = lane >> 4;

    const int nt0 = blockIdx.x * 64;   // HWSZ % 64 == 0 -> tile within one batch
    const int b   = nt0 / HWSZ;
    const int hw0 = nt0 % HWSZ;

    // LDS: staging (hi/lo f16, padded pitch 40 shorts = 20 words = 4*odd -> conflict-free b128)
    __shared__ union {
        struct { _Float16 Ah[128 * 40]; _Float16 Al[128 * 40];
                 _Float16 Bh[64 * 40];  _Float16 Bl[64 * 40]; } s;
        struct { float tok[64 * 129]; float logit[64 * 4]; } e;   // pitch 129 -> router reads conflict-free
    } u;
    __shared__ float s1_l[128], t1_l[128];

    if (tid < 128) {
        float s = bn1_g[tid] / sqrtf(bn1_v[tid] + BNE);
        s1_l[tid] = s;
        t1_l[tid] = bn1_b[tid] - bn1_m[tid] * s;
    }

    f32x4 acc_m[2][4], acc_c[2][4];
    #pragma unroll
    for (int i = 0; i < 2; i++)
        #pragma unroll
        for (int j = 0; j < 4; j++) { acc_m[i][j] = zero4(); acc_c[i][j] = zero4(); }

    for (int kc = 0; kc < C1; kc += 32) {
        // stage A slice: w1[o][kc..kc+32), split hi/lo (lo scaled by 2^11 to stay fp16-normal)
        #pragma unroll
        for (int rep = 0; rep < 4; rep++) {
            int lin = rep * 256 + tid;
            int o   = lin >> 3;
            int k4  = (lin & 7) * 4;
            const float4 v = *(const float4*)&w1[(size_t)o * C1 + kc + k4];
            _Float16* ah = &u.s.Ah[o * 40 + k4];
            _Float16* al = &u.s.Al[o * 40 + k4];
            _Float16 h0 = (_Float16)v.x, h1 = (_Float16)v.y, h2 = (_Float16)v.z, h3 = (_Float16)v.w;
            ah[0] = h0; ah[1] = h1; ah[2] = h2; ah[3] = h3;
            al[0] = (_Float16)((v.x - (float)h0) * 2048.0f);
            al[1] = (_Float16)((v.y - (float)h1) * 2048.0f);
            al[2] = (_Float16)((v.z - (float)h2) * 2048.0f);
            al[3] = (_Float16)((v.w - (float)h3) * 2048.0f);
        }
        // stage B slice: x[b][kc..kc+32)[hw0..hw0+64), transposed to [token][k]
        {
            int i  = tid & 63;
            int kg = tid >> 6;
            #pragma unroll
            for (int r = 0; r < 2; r++) {
                int k4 = (kg * 2 + r) * 4;
                const float* xp = x + ((size_t)(b * C1 + kc + k4)) * HWSZ + hw0 + i;
                float v0 = xp[0], v1 = xp[HWSZ], v2 = xp[2 * HWSZ], v3 = xp[3 * HWSZ];
                _Float16* bh = &u.s.Bh[i * 40 + k4];
                _Float16* bl = &u.s.Bl[i * 40 + k4];
                _Float16 h0 = (_Float16)v0, h1 = (_Float16)v1, h2 = (_Float16)v2, h3 = (_Float16)v3;
                bh[0] = h0; bh[1] = h1; bh[2] = h2; bh[3] = h3;
                bl[0] = (_Float16)((v0 - (float)h0) * 2048.0f);
                bl[1] = (_Float16)((v1 - (float)h1) * 2048.0f);
                bl[2] = (_Float16)((v2 - (float)h2) * 2048.0f);
                bl[3] = (_Float16)((v3 - (float)h3) * 2048.0f);
            }
        }
        __syncthreads();

        f16x8 a_h[2], a_l[2], b_h[4], b_l[4];
        #pragma unroll
        for (int mt = 0; mt < 2; mt++) {
            int row = (wv * 2 + mt) * 16 + n15;
            a_h[mt] = *(const f16x8*)&u.s.Ah[row * 40 + quad * 8];
            a_l[mt] = *(const f16x8*)&u.s.Al[row * 40 + quad * 8];
        }
        #pragma unroll
        for (int nt = 0; nt < 4; nt++) {
            int row = nt * 16 + n15;
            b_h[nt] = *(const f16x8*)&u.s.Bh[row * 40 + quad * 8];
            b_l[nt] = *(const f16x8*)&u.s.Bl[row * 40 + quad * 8];
        }
        #pragma unroll
        for (int mt = 0; mt < 2; mt++)
            #pragma unroll
            for (int nt = 0; nt < 4; nt++) {
                acc_m[mt][nt] = __builtin_amdgcn_mfma_f32_16x16x32_f16(a_h[mt], b_h[nt], acc_m[mt][nt], 0, 0, 0);
                acc_c[mt][nt] = __builtin_amdgcn_mfma_f32_16x16x32_f16(a_l[mt], b_h[nt], acc_c[mt][nt], 0, 0, 0);
                acc_c[mt][nt] = __builtin_amdgcn_mfma_f32_16x16x32_f16(a_h[mt], b_l[nt], acc_c[mt][nt], 0, 0, 0);
            }
        __syncthreads();
    }

    // epilogue: BN + SiLU (precise expf), token tile to LDS fp32
    #pragma unroll
    for (int mt = 0; mt < 2; mt++)
        #pragma unroll
        for (int nt = 0; nt < 4; nt++)
            #pragma unroll
            for (int r = 0; r < 4; r++) {
                int o  = (wv * 2 + mt) * 16 + quad * 4 + r;
                int tk = nt * 16 + n15;
                float y1 = acc_m[mt][nt][r] + acc_c[mt][nt][r] * (1.0f / 2048.0f);
                float y  = y1 * s1_l[o] + t1_l[o];
                u.e.tok[tk * 129 + o] = y / (1.0f + expf(-y));
            }
    __syncthreads();

    // router logits: thread -> (token, expert)
    {
        int tk = tid >> 2;
        int e  = tid & 3;
        const float* trow = &u.e.tok[tk * 129];
        const float* wrow = &rw[e * CH];
        float a0 = 0.f, a1 = 0.f, a2 = 0.f, a3 = 0.f;
        #pragma unroll 8
        for (int c = 0; c < CH; c += 4) {
            a0 = fmaf(trow[c + 0], wrow[c + 0], a0);
            a1 = fmaf(trow[c + 1], wrow[c + 1], a1);
            a2 = fmaf(trow[c + 2], wrow[c + 2], a2);
            a3 = fmaf(trow[c + 3], wrow[c + 3], a3);
        }
        u.e.logit[tk * 4 + e] = ((a0 + a1) + (a2 + a3)) + rb[e];
    }
    __syncthreads();

    // top-2 (strict > keeps lowest index on ties, matching lax.top_k) + renormalized weights
    if (tid < 64) {
        const float* lg = &u.e.logit[tid * 4];
        float l0 = lg[0], l1 = lg[1], l2 = lg[2], l3 = lg[3];
        int i1 = 0; float m1 = l0;
        if (l1 > m1) { m1 = l1; i1 = 1; }
        if (l2 > m1) { m1 = l2; i1 = 2; }
        if (l3 > m1) { m1 = l3; i1 = 3; }
        int i2 = -1; float m2 = -3.4e38f;
        if (i1 != 0 && l0 > m2) { m2 = l0; i2 = 0; }
        if (i1 != 1 && l1 > m2) { m2 = l1; i2 = 1; }
        if (i1 != 2 && l2 > m2) { m2 = l2; i2 = 2; }
        if (i1 != 3 && l3 > m2) { m2 = l3; i2 = 3; }
        float p2 = expf(m2 - m1);
        float wa = 1.0f / (1.0f + p2);
        float wb = p2 * wa;
        float4 wout;
        wout.x = (i1 == 0) ? wa : ((i2 == 0) ? wb : 0.0f);
        wout.y = (i1 == 1) ? wa : ((i2 == 1) ? wb : 0.0f);
        wout.z = (i1 == 2) ? wa : ((i2 == 2) ? wb : 0.0f);
        wout.w = (i1 == 3) ? wa : ((i2 == 3) ? wb : 0.0f);
        *(float4*)&wd[(size_t)(nt0 + tid) * 4] = wout;
    }

    // copy tokens out as bf16 (n,c), coalesced
    #pragma unroll
    for (int rep = 0; rep < 8; rep++) {
        int lin = rep * 256 + tid;
        int n   = lin >> 5;
        int c4  = (lin & 31) * 4;
        const float* tp = &u.e.tok[n * 129 + c4];
        ushort4 pk;
        pk.x = f2bf(tp[0]); pk.y = f2bf(tp[1]); pk.z = f2bf(tp[2]); pk.w = f2bf(tp[3]);
        *(ushort4*)&tokens[(size_t)(nt0 + n) * CH + c4] = pk;
    }
}

// ---------------------------------------------------------------- k2: all 4 experts (bf16 MFMA) + BN + SiLU + weighted combine
__global__ __launch_bounds__(256, 2) void k2_experts(
    const unsigned short* __restrict__ tokens, const unsigned short* __restrict__ cen,
    const float* __restrict__ wd,
    const float* __restrict__ ebn_g, const float* __restrict__ ebn_b,
    const float* __restrict__ ebn_m, const float* __restrict__ ebn_v,
    unsigned short* __restrict__ moe)
{
    const int tid  = threadIdx.x;
    const int lane = tid & 63;
    const int wv   = tid >> 6;
    const int n15  = lane & 15;
    const int quad = lane >> 4;
    const int nt0  = blockIdx.x * 64;

    __shared__ unsigned short Bt[64 * 136];    // tokens tile [tok][c], pitch 136 shorts = 68 words = 4*17
    __shared__ unsigned short Ac[128 * 136];   // one expert's center [o][c]
    __shared__ float wd_l[256];                // [tok][e]
    __shared__ float inv_l[512], sh_l[512];    // [e*128+o]

    #pragma unroll
    for (int rep = 0; rep < 4; rep++) {
        int lin = rep * 256 + tid;
        int n   = lin >> 4;
        int c8  = (lin & 15) * 8;
        *(uint4*)&Bt[n * 136 + c8] = *(const uint4*)&tokens[(size_t)(nt0 + n) * CH + c8];
    }
    wd_l[tid] = wd[(size_t)nt0 * 4 + tid];
    #pragma unroll
    for (int r = 0; r < 2; r++) {
        int idx = r * 256 + tid;               // e*128+o
        float iv = ebn_g[idx] / sqrtf(ebn_v[idx] + BNE);
        inv_l[idx] = iv;
        sh_l[idx]  = ebn_b[idx] - ebn_m[idx] * iv;
    }

    f32x4 oacc[2][4];
    #pragma unroll
    for (int i = 0; i < 2; i++)
        #pragma unroll
        for (int j = 0; j < 4; j++) oacc[i][j] = zero4();

    for (int e = 0; e < NEXP; e++) {
        __syncthreads();   // staging below overwrites Ac; also publishes Bt/wd/inv on e==0
        #pragma unroll
        for (int rep = 0; rep < 8; rep++) {
            int lin = rep * 256 + tid;
            int o   = lin >> 4;
            int c8  = (lin & 15) * 8;
            *(uint4*)&Ac[o * 136 + c8] = *(const uint4*)&cen[(size_t)e * CH * CH + o * CH + c8];
        }
        __syncthreads();

        f32x4 acc[2][4];
        #pragma unroll
        for (int i = 0; i < 2; i++)
            #pragma unroll
            for (int j = 0; j < 4; j++) acc[i][j] = zero4();

        #pragma unroll
        for (int kk = 0; kk < 4; kk++) {
            int ko = kk * 32 + quad * 8;
            s16x8 a0 = *(const s16x8*)&Ac[((wv * 2 + 0) * 16 + n15) * 136 + ko];
            s16x8 a1 = *(const s16x8*)&Ac[((wv * 2 + 1) * 16 + n15) * 136 + ko];
            s16x8 b0 = *(const s16x8*)&Bt[(0 * 16 + n15) * 136 + ko];
            s16x8 b1 = *(const s16x8*)&Bt[(1 * 16 + n15) * 136 + ko];
            s16x8 b2 = *(const s16x8*)&Bt[(2 * 16 + n15) * 136 + ko];
            s16x8 b3 = *(const s16x8*)&Bt[(3 * 16 + n15) * 136 + ko];
            acc[0][0] = __builtin_amdgcn_mfma_f32_16x16x32_bf16(a0, b0, acc[0][0], 0, 0, 0);
            acc[0][1] = __builtin_amdgcn_mfma_f32_16x16x32_bf16(a0, b1, acc[0][1], 0, 0, 0);
            acc[0][2] = __builtin_amdgcn_mfma_f32_16x16x32_bf16(a0, b2, acc[0][2], 0, 0, 0);
            acc[0][3] = __builtin_amdgcn_mfma_f32_16x16x32_bf16(a0, b3, acc[0][3], 0, 0, 0);
            acc[1][0] = __builtin_amdgcn_mfma_f32_16x16x32_bf16(a1, b0, acc[1][0], 0, 0, 0);
            acc[1][1] = __builtin_amdgcn_mfma_f32_16x16x32_bf16(a1, b1, acc[1][1], 0, 0, 0);
            acc[1][2] = __builtin_amdgcn_mfma_f32_16x16x32_bf16(a1, b2, acc[1][2], 0, 0, 0);
            acc[1][3] = __builtin_amdgcn_mfma_f32_16x16x32_bf16(a1, b3, acc[1][3], 0, 0, 0);
        }

        // BN + SiLU + router-weighted accumulate
        #pragma unroll
        for (int mt = 0; mt < 2; mt++)
            #pragma unroll
            for (int nt = 0; nt < 4; nt++) {
                float wde = wd_l[(nt * 16 + n15) * 4 + e];
                #pragma unroll
                for (int r = 0; r < 4; r++) {
                    int o = (wv * 2 + mt) * 16 + quad * 4 + r;
                    float y = acc[mt][nt][r] * inv_l[e * CH + o] + sh_l[e * CH + o];
                    oacc[mt][nt][r] += wde * (y / (1.0f + __expf(-y)));
                }
            }
    }

    // write moe tokens bf16 (n,c)
    #pragma unroll
    for (int mt = 0; mt < 2; mt++)
        #pragma unroll
        for (int nt = 0; nt < 4; nt++) {
            int tk = nt * 16 + n15;
            int ob = (wv * 2 + mt) * 16 + quad * 4;
            ushort4 pk;
            pk.x = f2bf(oacc[mt][nt][0]); pk.y = f2bf(oacc[mt][nt][1]);
            pk.z = f2bf(oacc[mt][nt][2]); pk.w = f2bf(oacc[mt][nt][3]);
            *(ushort4*)&moe[(size_t)(nt0 + tk) * CH + ob] = pk;
        }
}

// ---------------------------------------------------------------- k3: conv3 (bf16 MFMA) + BN + SiLU + residual
__global__ __launch_bounds__(256, 2) void k3_conv3(
    const unsigned short* __restrict__ moe, const float* __restrict__ w3,
    const float* __restrict__ bn3_g, const float* __restrict__ bn3_b,
    const float* __restrict__ bn3_m, const float* __restrict__ bn3_v,
    const float* __restrict__ x, float* __restrict__ out)
{
    const int tid  = threadIdx.x;
    const int lane = tid & 63;
    const int wv   = tid >> 6;
    const int n15  = lane & 15;
    const int quad = lane >> 4;
    const int nt0  = blockIdx.x * 64;
    const int b    = nt0 / HWSZ;
    const int hw0  = nt0 % HWSZ;

    __shared__ unsigned short A3[256 * 40];    // w3 slice [o2][k], pitch 40
    __shared__ unsigned short B3[64 * 40];     // moe slice [tok][k]
    __shared__ float s3_l[256], t3_l[256];

    {
        float s = bn3_g[tid] / sqrtf(bn3_v[tid] + BNE);
        s3_l[tid] = s;
        t3_l[tid] = bn3_b[tid] - bn3_m[tid] * s;
    }

    f32x4 acc[4][4];
    #pragma unroll
    for (int i = 0; i < 4; i++)
        #pragma unroll
        for (int j = 0; j < 4; j++) acc[i][j] = zero4();

    for (int kc = 0; kc < CH; kc += 32) {
        #pragma unroll
        for (int rep = 0; rep < 8; rep++) {
            int lin = rep * 256 + tid;
            int o   = lin >> 3;
            int k4  = (lin & 7) * 4;
            const float4 v = *(const float4*)&w3[(size_t)o * CH + kc + k4];
            ushort4 pk;
            pk.x = f2bf(v.x); pk.y = f2bf(v.y); pk.z = f2bf(v.z); pk.w = f2bf(v.w);
            *(ushort4*)&A3[o * 40 + k4] = pk;
        }
        #pragma unroll
        for (int rep = 0; rep < 2; rep++) {
            int lin = rep * 256 + tid;
            int n   = lin >> 3;
            int k4  = (lin & 7) * 4;
            *(ushort4*)&B3[n * 40 + k4] = *(const ushort4*)&moe[(size_t)(nt0 + n) * CH + kc + k4];
        }
        __syncthreads();

        s16x8 bf[4];
        #pragma unroll
        for (int nt = 0; nt < 4; nt++)
            bf[nt] = *(const s16x8*)&B3[(nt * 16 + n15) * 40 + quad * 8];
        #pragma unroll
        for (int mt = 0; mt < 4; mt++) {
            s16x8 af = *(const s16x8*)&A3[((wv * 4 + mt) * 16 + n15) * 40 + quad * 8];
            #pragma unroll
            for (int nt = 0; nt < 4; nt++)
                acc[mt][nt] = __builtin_amdgcn_mfma_f32_16x16x32_bf16(af, bf[nt], acc[mt][nt], 0, 0, 0);
        }
        __syncthreads();
    }

    #pragma unroll
    for (int mt = 0; mt < 4; mt++)
        #pragma unroll
        for (int nt = 0; nt < 4; nt++)
            #pragma unroll
            for (int r = 0; r < 4; r++) {
                int o2 = (wv * 4 + mt) * 16 + quad * 4 + r;
                int tk = nt * 16 + n15;
                size_t g = ((size_t)(b * C2 + o2)) * HWSZ + hw0 + tk;
                float y = acc[mt][nt][r] * s3_l[o2] + t3_l[o2];
                out[g] = y / (1.0f + __expf(-y)) + x[g];
            }
}

// ----------------------------------------------------------------
extern "C" void kernel_launch(void* const* d_in, const int* in_sizes, int n_in,
                              void* d_out, int out_size, void* d_ws, size_t ws_size,
                              hipStream_t stream) {
    const float* x     = (const float*)d_in[0];
    const float* w1    = (const float*)d_in[1];
    const float* bn1_g = (const float*)d_in[2];
    const float* bn1_b = (const float*)d_in[3];
    const float* bn1_m = (const float*)d_in[4];
    const float* bn1_v = (const float*)d_in[5];
    const float* rw    = (const float*)d_in[6];
    const float* rb    = (const float*)d_in[7];
    const float* ew    = (const float*)d_in[8];
    const float* ebn_g = (const float*)d_in[9];
    const float* ebn_b = (const float*)d_in[10];
    const float* ebn_m = (const float*)d_in[11];
    const float* ebn_v = (const float*)d_in[12];
    const float* w3    = (const float*)d_in[13];
    const float* bn3_g = (const float*)d_in[14];
    const float* bn3_b = (const float*)d_in[15];
    const float* bn3_m = (const float*)d_in[16];
    const float* bn3_v = (const float*)d_in[17];
    float* out = (float*)d_out;

    char* ws = (char*)d_ws;
    unsigned short* tokens = (unsigned short*)(ws);                           // N*128 bf16 = 52,428,800 B
    unsigned short* moe    = (unsigned short*)(ws + 52428800);                // N*128 bf16
    float*          wdv    = (float*)(ws + 104857600);                        // N*4 f32 = 3,276,800 B
    unsigned short* cen    = (unsigned short*)(ws + 104857600 + 3276800);     // 4*128*128 bf16

    k0_pack_center<<<dim3(256),  dim3(256), 0, stream>>>(ew, cen);
    k1_conv1_router<<<dim3(3200), dim3(256), 0, stream>>>(x, w1, bn1_g, bn1_b, bn1_m, bn1_v,
                                                          rw, rb, tokens, wdv);
    k2_experts<<<dim3(3200), dim3(256), 0, stream>>>(tokens, cen, wdv,
                                                     ebn_g, ebn_b, ebn_m, ebn_v, moe);
    k3_conv3<<<dim3(3200), dim3(256), 0, stream>>>(moe, w3, bn3_g, bn3_b, bn3_m, bn3_v, x, out);
    (void)in_sizes; (void)n_in; (void)out_size; (void)ws_size;
}

// Round 2
// 642.994 us; speedup vs baseline: 1.0589x; 1.0589x over previous
//
#include <hip/hip_runtime.h>
#include <cstdint>
#include <cstddef>

#define NEXP 4
#define CH   128      // c_
#define C1   256
#define C2   256
#define HWSZ 6400     // 80*80
#define NTOKS 204800  // 32*6400
#define BNE  1e-3f

using f32x4 = __attribute__((ext_vector_type(4))) float;
using f16x8 = __attribute__((ext_vector_type(8))) _Float16;
using s16x8 = __attribute__((ext_vector_type(8))) short;

static __device__ __forceinline__ unsigned short f2bf(float f) {
    union { float f; unsigned u; } v; v.f = f;
    unsigned r = v.u + 0x7fffu + ((v.u >> 16) & 1u);
    return (unsigned short)(r >> 16);
}
static __device__ __forceinline__ f32x4 zero4() {
    f32x4 z; z[0] = 0.f; z[1] = 0.f; z[2] = 0.f; z[3] = 0.f; return z;
}
// async global->LDS, 16B per lane. lds arg per-lane = wave_base + lane*16.
static __device__ __forceinline__ void g2lds16(const void* g, void* l) {
    __builtin_amdgcn_global_load_lds(
        (const __attribute__((address_space(1))) void*)g,
        (__attribute__((address_space(3))) void*)l, 16, 0, 0);
}

// ---------------------------------------------------------------- k0: pack weights once
// blocks [0,256): cen = bf16 ew[:,:,:,1,1]  (4*128*128)
// blocks [256,384): w1s = Dekker hi/lo f16 split of w1, layout [slice8][part2][o128][k32]
// blocks [384,512): w3p = bf16 w3, layout [slice4][o256][k32]
__global__ __launch_bounds__(256) void k0_pack(const float* __restrict__ ew,
                                               const float* __restrict__ w1,
                                               const float* __restrict__ w3,
                                               unsigned short* __restrict__ cen,
                                               _Float16* __restrict__ w1s,
                                               unsigned short* __restrict__ w3p) {
    int bid = blockIdx.x;
    int tid = threadIdx.x;
    if (bid < 256) {
        int idx = bid * 256 + tid;                       // (e*128+o)*128+c
        cen[idx] = f2bf(ew[(size_t)idx * 9 + 4]);
    } else if (bid < 384) {
        int lin = (bid - 256) * 256 + tid;               // 0..32767
        int o = lin >> 8, k = lin & 255;
        int s = k >> 5, kk = k & 31;
        float v = w1[o * C1 + k];
        _Float16 h = (_Float16)v;
        w1s[((s * 2 + 0) * 128 + o) * 32 + kk] = h;
        w1s[((s * 2 + 1) * 128 + o) * 32 + kk] = (_Float16)((v - (float)h) * 2048.0f);
    } else {
        int lin = (bid - 384) * 256 + tid;               // 0..32767
        int o = lin >> 7, k = lin & 127;
        int s = k >> 5, kk = k & 31;
        w3p[(s * 256 + o) * 32 + kk] = f2bf(w3[o * CH + k]);
    }
}

// ---------------------------------------------------------------- k1: conv1 (fp16x2-split MFMA) + BN + SiLU + router
// grid 3200 x 64 tokens. A (w1 hi/lo) DMA'd from presplit global; B (x) split on the fly.
__global__ __launch_bounds__(256, 2) void k1_conv1_router(
    const float* __restrict__ x, const _Float16* __restrict__ w1s,
    const float* __restrict__ bn1_g, const float* __restrict__ bn1_b,
    const float* __restrict__ bn1_m, const float* __restrict__ bn1_v,
    const float* __restrict__ rw, const float* __restrict__ rb,
    unsigned short* __restrict__ tokens, float* __restrict__ wd)
{
    const int tid  = threadIdx.x;
    const int lane = tid & 63;
    const int n15  = lane & 15;
    const int quad = lane >> 4;
    const int wv   = tid >> 6;

    const int nt0 = blockIdx.x * 64;
    const int b   = nt0 / HWSZ;
    const int hw0 = nt0 % HWSZ;

    __shared__ union {
        struct { _Float16 Ahl[2 * 128 * 32];             // hi plane then lo plane, DMA target (unpadded)
                 _Float16 Bh[64 * 40]; _Float16 Bl[64 * 40]; } s;   // B padded pitch 40
        struct { float tok[64 * 129]; float logit[64 * 4]; } e;
    } u;
    __shared__ float s1_l[128], t1_l[128];

    if (tid < 128) {
        float s = bn1_g[tid] / sqrtf(bn1_v[tid] + BNE);
        s1_l[tid] = s;
        t1_l[tid] = bn1_b[tid] - bn1_m[tid] * s;
    }

    f32x4 acc_m[2][4], acc_c[2][4];
    #pragma unroll
    for (int i = 0; i < 2; i++)
        #pragma unroll
        for (int j = 0; j < 4; j++) { acc_m[i][j] = zero4(); acc_c[i][j] = zero4(); }

    const char* w1b = (const char*)w1s;
    char*       Ab  = (char*)u.s.Ahl;

    for (int s = 0; s < 8; s++) {
        // A slice (16 KB: hi 8KB + lo 8KB) via async DMA, zero VALU conversion
        {
            const char* src = w1b + s * 16384 + tid * 16;
            char*       dst = Ab + tid * 16;
            g2lds16(src + 0,     dst + 0);
            g2lds16(src + 4096,  dst + 4096);
            g2lds16(src + 8192,  dst + 8192);
            g2lds16(src + 12288, dst + 12288);
        }
        // B slice: x[b][s*32..+32)[hw0..+64) transposed + split
        {
            int i  = tid & 63;
            int kg = tid >> 6;
            #pragma unroll
            for (int r = 0; r < 2; r++) {
                int k4 = (kg * 2 + r) * 4;
                const float* xp = x + ((size_t)(b * C1 + s * 32 + k4)) * HWSZ + hw0 + i;
                float v0 = xp[0], v1 = xp[HWSZ], v2 = xp[2 * HWSZ], v3 = xp[3 * HWSZ];
                _Float16* bh = &u.s.Bh[i * 40 + k4];
                _Float16* bl = &u.s.Bl[i * 40 + k4];
                _Float16 h0 = (_Float16)v0, h1 = (_Float16)v1, h2 = (_Float16)v2, h3 = (_Float16)v3;
                bh[0] = h0; bh[1] = h1; bh[2] = h2; bh[3] = h3;
                bl[0] = (_Float16)((v0 - (float)h0) * 2048.0f);
                bl[1] = (_Float16)((v1 - (float)h1) * 2048.0f);
                bl[2] = (_Float16)((v2 - (float)h2) * 2048.0f);
                bl[3] = (_Float16)((v3 - (float)h3) * 2048.0f);
            }
        }
        __syncthreads();

        f16x8 a_h[2], a_l[2];
        #pragma unroll
        for (int mt = 0; mt < 2; mt++) {
            int row = (wv * 2 + mt) * 16 + n15;
            a_h[mt] = *(const f16x8*)&u.s.Ahl[row * 32 + quad * 8];
            a_l[mt] = *(const f16x8*)&u.s.Ahl[4096 + row * 32 + quad * 8];
        }
        #pragma unroll
        for (int nt = 0; nt < 4; nt++) {
            int row = nt * 16 + n15;
            f16x8 b_h = *(const f16x8*)&u.s.Bh[row * 40 + quad * 8];
            f16x8 b_l = *(const f16x8*)&u.s.Bl[row * 40 + quad * 8];
            #pragma unroll
            for (int mt = 0; mt < 2; mt++) {
                acc_m[mt][nt] = __builtin_amdgcn_mfma_f32_16x16x32_f16(a_h[mt], b_h, acc_m[mt][nt], 0, 0, 0);
                acc_c[mt][nt] = __builtin_amdgcn_mfma_f32_16x16x32_f16(a_l[mt], b_h, acc_c[mt][nt], 0, 0, 0);
                acc_c[mt][nt] = __builtin_amdgcn_mfma_f32_16x16x32_f16(a_h[mt], b_l, acc_c[mt][nt], 0, 0, 0);
            }
        }
        __syncthreads();
    }

    // epilogue: BN + SiLU (precise expf) into fp32 LDS token tile
    #pragma unroll
    for (int mt = 0; mt < 2; mt++)
        #pragma unroll
        for (int nt = 0; nt < 4; nt++)
            #pragma unroll
            for (int r = 0; r < 4; r++) {
                int o  = (wv * 2 + mt) * 16 + quad * 4 + r;
                int tk = nt * 16 + n15;
                float y1 = acc_m[mt][nt][r] + acc_c[mt][nt][r] * (1.0f / 2048.0f);
                float y  = y1 * s1_l[o] + t1_l[o];
                u.e.tok[tk * 129 + o] = y / (1.0f + expf(-y));
            }
    __syncthreads();

    // router logits
    {
        int tk = tid >> 2;
        int e  = tid & 3;
        const float* trow = &u.e.tok[tk * 129];
        const float* wrow = &rw[e * CH];
        float a0 = 0.f, a1 = 0.f, a2 = 0.f, a3 = 0.f;
        #pragma unroll 8
        for (int c = 0; c < CH; c += 4) {
            a0 = fmaf(trow[c + 0], wrow[c + 0], a0);
            a1 = fmaf(trow[c + 1], wrow[c + 1], a1);
            a2 = fmaf(trow[c + 2], wrow[c + 2], a2);
            a3 = fmaf(trow[c + 3], wrow[c + 3], a3);
        }
        u.e.logit[tk * 4 + e] = ((a0 + a1) + (a2 + a3)) + rb[e];
    }
    __syncthreads();

    // top-2 (strict >, lowest index on ties) + renormalized softmax weights
    if (tid < 64) {
        const float* lg = &u.e.logit[tid * 4];
        float l0 = lg[0], l1 = lg[1], l2 = lg[2], l3 = lg[3];
        int i1 = 0; float m1 = l0;
        if (l1 > m1) { m1 = l1; i1 = 1; }
        if (l2 > m1) { m1 = l2; i1 = 2; }
        if (l3 > m1) { m1 = l3; i1 = 3; }
        int i2 = -1; float m2 = -3.4e38f;
        if (i1 != 0 && l0 > m2) { m2 = l0; i2 = 0; }
        if (i1 != 1 && l1 > m2) { m2 = l1; i2 = 1; }
        if (i1 != 2 && l2 > m2) { m2 = l2; i2 = 2; }
        if (i1 != 3 && l3 > m2) { m2 = l3; i2 = 3; }
        float p2 = expf(m2 - m1);
        float wa = 1.0f / (1.0f + p2);
        float wb = p2 * wa;
        float4 wout;
        wout.x = (i1 == 0) ? wa : ((i2 == 0) ? wb : 0.0f);
        wout.y = (i1 == 1) ? wa : ((i2 == 1) ? wb : 0.0f);
        wout.z = (i1 == 2) ? wa : ((i2 == 2) ? wb : 0.0f);
        wout.w = (i1 == 3) ? wa : ((i2 == 3) ? wb : 0.0f);
        *(float4*)&wd[(size_t)(nt0 + tid) * 4] = wout;
    }

    // tokens out as bf16 (n,c)
    #pragma unroll
    for (int rep = 0; rep < 8; rep++) {
        int lin = rep * 256 + tid;
        int n   = lin >> 5;
        int c4  = (lin & 31) * 4;
        const float* tp = &u.e.tok[n * 129 + c4];
        ushort4 pk;
        pk.x = f2bf(tp[0]); pk.y = f2bf(tp[1]); pk.z = f2bf(tp[2]); pk.w = f2bf(tp[3]);
        *(ushort4*)&tokens[(size_t)(nt0 + n) * CH + c4] = pk;
    }
}

// ---------------------------------------------------------------- k2: 4 experts + BN + SiLU + weighted combine
// grid 1600 x 128 tokens; 4 waves tile the 128x128 output as 64x64 quadrants.
__global__ __launch_bounds__(256, 2) void k2_experts(
    const unsigned short* __restrict__ tokens, const unsigned short* __restrict__ cen,
    const float* __restrict__ wd,
    const float* __restrict__ ebn_g, const float* __restrict__ ebn_b,
    const float* __restrict__ ebn_m, const float* __restrict__ ebn_v,
    unsigned short* __restrict__ moe)
{
    const int tid  = threadIdx.x;
    const int lane = tid & 63;
    const int wv   = tid >> 6;
    const int n15  = lane & 15;
    const int quad = lane >> 4;
    const int qm   = wv & 1;        // o-half
    const int qn   = wv >> 1;       // token-half
    const int nt0  = blockIdx.x * 128;

    __shared__ unsigned short Bt[128 * 136];   // tokens [tok][c] pitch 136
    __shared__ unsigned short Ac[128 * 136];   // one expert's center [o][c]
    __shared__ float wd_l[512];                // [tok][e]
    __shared__ float inv_l[512], sh_l[512];    // [e*128+o]

    #pragma unroll
    for (int rep = 0; rep < 8; rep++) {
        int lin = rep * 256 + tid;
        int n   = lin >> 4;
        int c8  = (lin & 15) * 8;
        *(uint4*)&Bt[n * 136 + c8] = *(const uint4*)&tokens[(size_t)(nt0 + n) * CH + c8];
    }
    wd_l[tid]       = wd[(size_t)nt0 * 4 + tid];
    wd_l[256 + tid] = wd[(size_t)nt0 * 4 + 256 + tid];
    #pragma unroll
    for (int r = 0; r < 2; r++) {
        int idx = r * 256 + tid;
        float iv = ebn_g[idx] / sqrtf(ebn_v[idx] + BNE);
        inv_l[idx] = iv;
        sh_l[idx]  = ebn_b[idx] - ebn_m[idx] * iv;
    }

    f32x4 oacc[4][4];
    #pragma unroll
    for (int i = 0; i < 4; i++)
        #pragma unroll
        for (int j = 0; j < 4; j++) oacc[i][j] = zero4();

    for (int e = 0; e < NEXP; e++) {
        __syncthreads();
        #pragma unroll
        for (int rep = 0; rep < 8; rep++) {
            int lin = rep * 256 + tid;
            int o   = lin >> 4;
            int c8  = (lin & 15) * 8;
            *(uint4*)&Ac[o * 136 + c8] = *(const uint4*)&cen[(size_t)e * CH * CH + o * CH + c8];
        }
        __syncthreads();

        f32x4 acc[4][4];
        #pragma unroll
        for (int i = 0; i < 4; i++)
            #pragma unroll
            for (int j = 0; j < 4; j++) acc[i][j] = zero4();

        #pragma unroll
        for (int kk = 0; kk < 4; kk++) {
            int ko = kk * 32 + quad * 8;
            s16x8 a[4], bb[4];
            #pragma unroll
            for (int i = 0; i < 4; i++) {
                a[i]  = *(const s16x8*)&Ac[(qm * 64 + i * 16 + n15) * 136 + ko];
                bb[i] = *(const s16x8*)&Bt[(qn * 64 + i * 16 + n15) * 136 + ko];
            }
            #pragma unroll
            for (int mt = 0; mt < 4; mt++)
                #pragma unroll
                for (int nt = 0; nt < 4; nt++)
                    acc[mt][nt] = __builtin_amdgcn_mfma_f32_16x16x32_bf16(a[mt], bb[nt], acc[mt][nt], 0, 0, 0);
        }

        #pragma unroll
        for (int mt = 0; mt < 4; mt++)
            #pragma unroll
            for (int nt = 0; nt < 4; nt++) {
                float wde = wd_l[(qn * 64 + nt * 16 + n15) * 4 + e];
                #pragma unroll
                for (int r = 0; r < 4; r++) {
                    int o = qm * 64 + mt * 16 + quad * 4 + r;
                    float y = acc[mt][nt][r] * inv_l[e * CH + o] + sh_l[e * CH + o];
                    oacc[mt][nt][r] += wde * (y / (1.0f + __expf(-y)));
                }
            }
    }

    #pragma unroll
    for (int mt = 0; mt < 4; mt++)
        #pragma unroll
        for (int nt = 0; nt < 4; nt++) {
            int tk = qn * 64 + nt * 16 + n15;
            int ob = qm * 64 + mt * 16 + quad * 4;
            ushort4 pk;
            pk.x = f2bf(oacc[mt][nt][0]); pk.y = f2bf(oacc[mt][nt][1]);
            pk.z = f2bf(oacc[mt][nt][2]); pk.w = f2bf(oacc[mt][nt][3]);
            *(ushort4*)&moe[(size_t)(nt0 + tk) * CH + ob] = pk;
        }
}

// ---------------------------------------------------------------- k3: conv3 (bf16 MFMA, presplit w3 via DMA) + BN + SiLU + residual
__global__ __launch_bounds__(256, 2) void k3_conv3(
    const unsigned short* __restrict__ moe, const unsigned short* __restrict__ w3p,
    const float* __restrict__ bn3_g, const float* __restrict__ bn3_b,
    const float* __restrict__ bn3_m, const float* __restrict__ bn3_v,
    const float* __restrict__ x, float* __restrict__ out)
{
    const int tid  = threadIdx.x;
    const int lane = tid & 63;
    const int wv   = tid >> 6;
    const int n15  = lane & 15;
    const int quad = lane >> 4;
    const int nt0  = blockIdx.x * 64;
    const int b    = nt0 / HWSZ;
    const int hw0  = nt0 % HWSZ;

    __shared__ unsigned short A3[256 * 32];    // w3 slice [o][k] unpadded (DMA target)
    __shared__ unsigned short B3[64 * 40];     // moe slice [tok][k] pitch 40
    __shared__ float s3_l[256], t3_l[256];

    {
        float s = bn3_g[tid] / sqrtf(bn3_v[tid] + BNE);
        s3_l[tid] = s;
        t3_l[tid] = bn3_b[tid] - bn3_m[tid] * s;
    }

    f32x4 acc[4][4];
    #pragma unroll
    for (int i = 0; i < 4; i++)
        #pragma unroll
        for (int j = 0; j < 4; j++) acc[i][j] = zero4();

    const char* w3b = (const char*)w3p;
    char*       Ab  = (char*)A3;

    for (int s = 0; s < 4; s++) {
        {
            const char* src = w3b + s * 16384 + tid * 16;
            char*       dst = Ab + tid * 16;
            g2lds16(src + 0,     dst + 0);
            g2lds16(src + 4096,  dst + 4096);
            g2lds16(src + 8192,  dst + 8192);
            g2lds16(src + 12288, dst + 12288);
        }
        #pragma unroll
        for (int rep = 0; rep < 2; rep++) {
            int lin = rep * 256 + tid;
            int n   = lin >> 3;
            int k4  = (lin & 7) * 4;
            *(ushort4*)&B3[n * 40 + k4] = *(const ushort4*)&moe[(size_t)(nt0 + n) * CH + s * 32 + k4];
        }
        __syncthreads();

        s16x8 bf[4];
        #pragma unroll
        for (int nt = 0; nt < 4; nt++)
            bf[nt] = *(const s16x8*)&B3[(nt * 16 + n15) * 40 + quad * 8];
        #pragma unroll
        for (int mt = 0; mt < 4; mt++) {
            s16x8 af = *(const s16x8*)&A3[((wv * 4 + mt) * 16 + n15) * 32 + quad * 8];
            #pragma unroll
            for (int nt = 0; nt < 4; nt++)
                acc[mt][nt] = __builtin_amdgcn_mfma_f32_16x16x32_bf16(af, bf[nt], acc[mt][nt], 0, 0, 0);
        }
        __syncthreads();
    }

    #pragma unroll
    for (int mt = 0; mt < 4; mt++)
        #pragma unroll
        for (int nt = 0; nt < 4; nt++)
            #pragma unroll
            for (int r = 0; r < 4; r++) {
                int o2 = (wv * 4 + mt) * 16 + quad * 4 + r;
                int tk = nt * 16 + n15;
                size_t g = ((size_t)(b * C2 + o2)) * HWSZ + hw0 + tk;
                float y = acc[mt][nt][r] * s3_l[o2] + t3_l[o2];
                out[g] = y / (1.0f + __expf(-y)) + x[g];
            }
}

// ----------------------------------------------------------------
extern "C" void kernel_launch(void* const* d_in, const int* in_sizes, int n_in,
                              void* d_out, int out_size, void* d_ws, size_t ws_size,
                              hipStream_t stream) {
    const float* x     = (const float*)d_in[0];
    const float* w1    = (const float*)d_in[1];
    const float* bn1_g = (const float*)d_in[2];
    const float* bn1_b = (const float*)d_in[3];
    const float* bn1_m = (const float*)d_in[4];
    const float* bn1_v = (const float*)d_in[5];
    const float* rw    = (const float*)d_in[6];
    const float* rb    = (const float*)d_in[7];
    const float* ew    = (const float*)d_in[8];
    const float* ebn_g = (const float*)d_in[9];
    const float* ebn_b = (const float*)d_in[10];
    const float* ebn_m = (const float*)d_in[11];
    const float* ebn_v = (const float*)d_in[12];
    const float* w3    = (const float*)d_in[13];
    const float* bn3_g = (const float*)d_in[14];
    const float* bn3_b = (const float*)d_in[15];
    const float* bn3_m = (const float*)d_in[16];
    const float* bn3_v = (const float*)d_in[17];
    float* out = (float*)d_out;

    char* ws = (char*)d_ws;
    unsigned short* tokens = (unsigned short*)(ws);                // N*128 bf16
    unsigned short* moe    = (unsigned short*)(ws + 52428800);     // N*128 bf16
    float*          wdv    = (float*)(ws + 104857600);             // N*4 f32
    unsigned short* cen    = (unsigned short*)(ws + 108134400);    // 4*128*128 bf16 = 131072 B
    _Float16*       w1s    = (_Float16*)(ws + 108265472);          // 2*128*256 f16 = 131072 B
    unsigned short* w3p    = (unsigned short*)(ws + 108396544);    // 256*128 bf16 = 65536 B

    k0_pack<<<dim3(512), dim3(256), 0, stream>>>(ew, w1, w3, cen, w1s, w3p);
    k1_conv1_router<<<dim3(3200), dim3(256), 0, stream>>>(x, w1s, bn1_g, bn1_b, bn1_m, bn1_v,
                                                          rw, rb, tokens, wdv);
    k2_experts<<<dim3(1600), dim3(256), 0, stream>>>(tokens, cen, wdv,
                                                     ebn_g, ebn_b, ebn_m, ebn_v, moe);
    k3_conv3<<<dim3(3200), dim3(256), 0, stream>>>(moe, w3p, bn3_g, bn3_b, bn3_m, bn3_v, x, out);
    (void)in_sizes; (void)n_in; (void)out_size; (void)ws_size;
}